// Round 9
// baseline (393.876 us; speedup 1.0000x reference)
//
#include <hip/hip_runtime.h>

// Propagation: E = softsign(V V^T / sqrt(D)); out0 = E @ state; out1 = E @ V
// B=4, N=4096, D=256, fp32 in/out.
//
// Round 15 (base R9 @ 86.0us prop_main; R12/R14 isolated: swizzle +3.6,
// pins ~0, counted-vmcnt ~0 -> the limiter is 2 barrier domains/CU, and
// occupancy is GRID-limited, not LDS-limited):
//  - 4 blocks/CU: grid 1024 = b(4) x it(64) x jq(4 quarters), niter=16,
//    same 64 i-rows & per-wave work. LDS shrunk to EXACTLY 40960B:
//    vj SINGLE buffer 32KB (DMA for k+1 issued after B2 into same buffer;
//    G1(k) reads drained by B2's lgkmcnt, completion enforced at B1(k+1);
//    window = G2 phase >= 600cy vs ~200-400cy L2-hit -- feeds are pinned
//    L2-resident), Esh [64][64] swizzled 8KB (72-pad doesn't fit; -3.6us
//    risk accepted for the 4th block), stj dropped (state read direct),
//    dsred aliases dead vj region post-loop.
//  - launch_bounds(256,4) -> VGPR cap 128 (R9 measured 124 same payload).
//  - Partials 4-way bf16 (err ~0.1 << tol 4.0) -> combine traffic flat,
//    ws need stays exactly 50,462,720 B (== old need).
//  - XCD pin: x%8 = b*2 + (jq>>1) -> ~2-3MB/XCD < 4MB L2.
//  - softsign folded: e = s/(16+|s|)  (== (s/16)/(1+|s/16|)).
//  - fallback: round-1 fused kernel if ws too small.

#define B_  4
#define N_  4096
#define D_  256

typedef __attribute__((ext_vector_type(8))) short short8;
typedef __attribute__((ext_vector_type(8))) unsigned short ushort8v;
typedef __attribute__((ext_vector_type(4))) float floatx4;

__device__ __forceinline__ unsigned short f2bf(float f) {
    unsigned int u = __float_as_uint(f);
    u += 0x7fff + ((u >> 16) & 1);   // RTNE
    return (unsigned short)(u >> 16);
}
__device__ __forceinline__ float bf2f(unsigned short h) {
    return __uint_as_float((unsigned int)h << 16);
}

__device__ __forceinline__ void gl_lds16(const void* g, void* l) {
    __builtin_amdgcn_global_load_lds(
        (const __attribute__((address_space(1))) unsigned int*)g,
        (__attribute__((address_space(3))) unsigned int*)l, 16, 0, 0);
}

// ---------------- pre-pass: fp32 -> bf16 Vb (row-major) + fragment-ordered VF ----------------
// VF layout per batch: [jb 0..127][d 0..255][e 0..31], elem = V[jb*32+e][d].
__global__ __launch_bounds__(256)
void prepass_kernel(const float* __restrict__ val,
                    unsigned short* __restrict__ Vb,
                    unsigned short* __restrict__ VF) {
    __shared__ unsigned short tile[64][68];
    const int t   = threadIdx.x;
    const int blk = blockIdx.x;            // b*256 + it*4 + dt
    const int b   = blk >> 8;
    const int it  = (blk >> 2) & 63;
    const int dt  = blk & 3;
    const int i0  = it * 64, d0 = dt * 64;
    const float*    vb  = val + (size_t)b * N_ * D_;
    unsigned short* Vbb = Vb  + (size_t)b * N_ * D_;
    unsigned short* VFb = VF  + (size_t)b * N_ * D_;

    #pragma unroll
    for (int q = 0; q < 4; ++q) {
        int idx = t + 256 * q;
        int row = idx >> 4;
        int c4  = idx & 15;
        float4 v = *(const float4*)(vb + (size_t)(i0 + row) * D_ + d0 + c4 * 4);
        ushort4 h;
        h.x = f2bf(v.x); h.y = f2bf(v.y); h.z = f2bf(v.z); h.w = f2bf(v.w);
        *(ushort4*)(Vbb + (size_t)(i0 + row) * D_ + d0 + c4 * 4) = h;
        *(ushort4*)&tile[row][c4 * 4] = h;
    }
    __syncthreads();
    #pragma unroll
    for (int q = 0; q < 4; ++q) {
        int dr = (t >> 4) + q * 16;     // d within tile
        int i4 = t & 15;                 // j-quad within 64
        ushort4 h;
        h.x = tile[i4 * 4 + 0][dr];
        h.y = tile[i4 * 4 + 1][dr];
        h.z = tile[i4 * 4 + 2][dr];
        h.w = tile[i4 * 4 + 3][dr];
        const int jb = (i0 >> 5) + (i4 >> 3);
        const int e  = (i4 & 7) * 4;
        *(ushort4*)(VFb + ((size_t)jb * 256 + d0 + dr) * 32 + e) = h;
    }
}

// ---------------- main fused kernel ----------------
// grid 1024; decode: b=(x>>1)&3, jq=(x&1)*2+((x>>3)&1), it=x>>4.
// XCD pin: x%8 = b*2 + (jq>>1)... (x&1)=jq-high-bit, so per XCD: one b,
// one j-half (2 quarters) -> ~2-3MB L2 set.
// 256 threads = 4 waves; block covers 64 i-rows x 1024 j (quarter); 16 iters.
// LDS map (bytes), total 40960 (4 blocks/CU = 163840B = exactly 160KB):
//   vj   : 0       (32768)  [64 j][256 d] granule-swizzled, SINGLE buffer
//   Esh  : 32768   (8192)   [64][64] bf16, XOR-swizzled (block ^= row&7)
//   dsred: aliases vj region after the loop
__global__ __launch_bounds__(256, 4)
void prop_main(const float* __restrict__ state,
               const unsigned short* __restrict__ Vb,
               const unsigned short* __restrict__ VF,
               unsigned short* __restrict__ dvp,   // [4][B][N][D] bf16 partials
               unsigned short* __restrict__ dsp_o) // [4][B][N]    bf16 partials
{
    __shared__ __attribute__((aligned(16))) unsigned char smem[40960];

    const int t    = threadIdx.x;
    const int w    = t >> 6;          // wave 0..3
    const int lane = t & 63;
    const int quad = lane >> 4;
    const int l16  = lane & 15;
    const int l7   = lane & 7;

    const int x   = blockIdx.x;
    const int b   = (x >> 1) & 3;
    const int jq  = (x & 1) * 2 + ((x >> 3) & 1);
    const int it  = x >> 4;           // 0..63
    const int it0 = it * 64;
    const int jbase = jq * 1024;
    const int niter = 16;

    unsigned short* vjL  = (unsigned short*)smem;
    unsigned short* EshL = (unsigned short*)(smem + 32768);

    const unsigned short* Vbb = Vb + (size_t)b * N_ * D_;
    const unsigned short* VFb = VF + (size_t)b * N_ * D_;
    const float*          stb = state + (size_t)b * N_;

    const int hi  = lane >> 5;
    const int p32 = lane & 31;

    // per-wave staging offsets for vj (4 waves cooperatively stage 64 rows)
    int vgoff[8];   // vj: rows 2*(w*8+n)+hi, granule-swizzled
    #pragma unroll
    for (int n = 0; n < 8; ++n) {
        int r  = 2 * (w * 8 + n) + hi;           // 0..63
        int gr = p32 ^ (r & 7);
        vgoff[n] = r * 256 + gr * 8;
    }

    const int r0 = (w >> 1) * 32;     // GEMM1 row base
    const int c0 = (w & 1) * 32;      // GEMM1 col (j) base
    const int cB = (w & 1) * 4 + (l16 >> 3);  // Esh write col-block base

    // GEMM2 B-frag lane base in VF (contiguous 1KB per wave-load):
    // addr(k,ks,c2) = vf_lane + k*16384 + ks*8192 + c2*512   (elems)
    const unsigned short* vf_lane = VFb + (size_t)jq * 32 * 8192
                                  + (w * 64 + l16) * 32 + quad * 8;

    // ---- hoist GEMM1 A-fragments to registers (loop-invariant) ----
    short8 A0[8], A1[8];
    {
        const unsigned short* ar0 = Vbb + (size_t)(it0 + r0 + l16) * 256 + quad * 8;
        const unsigned short* ar1 = ar0 + 16 * 256;
        #pragma unroll
        for (int ks = 0; ks < 8; ++ks) {
            A0[ks] = *(const short8*)(ar0 + ks * 32);
            A1[ks] = *(const short8*)(ar1 + ks * 32);
        }
    }

    // ---- prologue: DMA tile 0 into vj ----
    #pragma unroll
    for (int n = 0; n < 8; ++n)
        gl_lds16(Vbb + (size_t)jbase * 256 + vgoff[n],
                 smem + (w * 8 + n) * 1024);

    floatx4 dv[4][4];
    #pragma unroll
    for (int a = 0; a < 4; ++a)
        #pragma unroll
        for (int c = 0; c < 4; ++c)
            dv[a][c] = (floatx4){0.f, 0.f, 0.f, 0.f};
    float dsp[8];
    #pragma unroll
    for (int k = 0; k < 8; ++k) dsp[k] = 0.f;

    for (int k = 0; k < niter; ++k) {
        __syncthreads();   // B1: vj(k) DMA drained & visible; prev GEMM2's
                           // Esh reads done (WAR for this iter's epilogue).

        const int j0 = jbase + k * 64;
        // state for this j-tile: L2-direct scalar loads (issued early)
        float stc0 = stb[j0 + c0 + l16];
        float stc1 = stb[j0 + c0 + 16 + l16];

        // ---- GEMM2 B-frags for THIS iter (dense L2-direct loads) ----
        short8 bfr[2][4];
        {
            const unsigned short* vfk = vf_lane + (size_t)k * 16384;
            #pragma unroll
            for (int ks = 0; ks < 2; ++ks)
                #pragma unroll
                for (int c2 = 0; c2 < 4; ++c2)
                    bfr[ks][c2] = *(const short8*)(vfk + ks * 8192 + c2 * 512);
        }

        // ---- GEMM1: S = Vi . Vj^T (K=256, A from registers, B from vj) ----
        floatx4 sa[2][2];
        #pragma unroll
        for (int a = 0; a < 2; ++a)
            #pragma unroll
            for (int c = 0; c < 2; ++c)
                sa[a][c] = (floatx4){0.f, 0.f, 0.f, 0.f};

        #pragma unroll
        for (int ks = 0; ks < 8; ++ks) {
            const int p = ((ks * 4 + quad) ^ l7) * 8;
            short8 b0 = *(const short8*)&vjL[(c0 + l16) * 256 + p];
            short8 b1 = *(const short8*)&vjL[(c0 + 16 + l16) * 256 + p];
            sa[0][0] = __builtin_amdgcn_mfma_f32_16x16x32_bf16(A0[ks], b0, sa[0][0], 0, 0, 0);
            sa[0][1] = __builtin_amdgcn_mfma_f32_16x16x32_bf16(A0[ks], b1, sa[0][1], 0, 0, 0);
            sa[1][0] = __builtin_amdgcn_mfma_f32_16x16x32_bf16(A1[ks], b0, sa[1][0], 0, 0, 0);
            sa[1][1] = __builtin_amdgcn_mfma_f32_16x16x32_bf16(A1[ks], b1, sa[1][1], 0, 0, 0);
        }

        // ---- softsign epilogue: e = s/(16+|s|) -> Esh (XOR-swizzled) ----
        #pragma unroll
        for (int a = 0; a < 2; ++a) {
            #pragma unroll
            for (int r = 0; r < 4; ++r) {
                const int il  = r0 + a * 16 + quad * 4 + r;
                const int ilb = (quad * 4 + r) & 7;      // == il & 7
                float s0 = sa[a][0][r];
                float s1 = sa[a][1][r];
                float e0 = s0 * __builtin_amdgcn_rcpf(16.0f + fabsf(s0));
                float e1 = s1 * __builtin_amdgcn_rcpf(16.0f + fabsf(s1));
                dsp[a * 4 + r] += e0 * stc0 + e1 * stc1;
                EshL[il * 64 + ((cB ^ ilb) << 3) + l7]       = f2bf(e0);
                EshL[il * 64 + (((cB + 2) ^ ilb) << 3) + l7] = f2bf(e1);
            }
        }
        __syncthreads();   // B2: Esh visible; G1's vj reads drained (lgkm) ->
                           // safe to overwrite vj below; bfr loads drained.

        // ---- DMA vj(k+1) into the SAME buffer (window: GEMM2 phase;
        //      completion enforced by B1 of iter k+1) ----
        if (k + 1 < niter) {
            const size_t j0n = (size_t)(jbase + (k + 1) * 64);
            #pragma unroll
            for (int n = 0; n < 8; ++n)
                gl_lds16(Vbb + j0n * 256 + vgoff[n],
                         smem + (w * 8 + n) * 1024);
        }

        // ---- GEMM2: dval += E . Vj (A from Esh, B from regs) ----
        #pragma unroll
        for (int ks = 0; ks < 2; ++ks) {
            short8 af[4];
            #pragma unroll
            for (int a2 = 0; a2 < 4; ++a2)
                af[a2] = *(const short8*)&EshL[(a2 * 16 + l16) * 64
                                               + (((ks * 4 + quad) ^ l7) << 3)];
            #pragma unroll
            for (int a2 = 0; a2 < 4; ++a2)
                #pragma unroll
                for (int c2 = 0; c2 < 4; ++c2)
                    dv[a2][c2] = __builtin_amdgcn_mfma_f32_16x16x32_bf16(af[a2], bfr[ks][c2], dv[a2][c2], 0, 0, 0);
        }
        // next B1 separates these Esh reads from the next epilogue's writes.
    }

    // ---- epilogue: bf16 partial delta_val for this (i-tile, j-quarter) ----
    unsigned short* dvo = dvp + ((size_t)jq * B_ + b) * N_ * D_
                        + (size_t)it0 * D_;
    #pragma unroll
    for (int a2 = 0; a2 < 4; ++a2)
        #pragma unroll
        for (int c2 = 0; c2 < 4; ++c2)
            #pragma unroll
            for (int r = 0; r < 4; ++r) {
                const int il = a2 * 16 + quad * 4 + r;
                const int d  = w * 64 + c2 * 16 + l16;
                dvo[(size_t)il * D_ + d] = f2bf(dv[a2][c2][r]);
            }

    // ---- epilogue: bf16 partial delta_state (dsred aliases dead vj) ----
    float* dsred = (float*)smem;
    #pragma unroll
    for (int k = 0; k < 8; ++k) {
        float v = dsp[k];
        v += __shfl_xor(v, 1);
        v += __shfl_xor(v, 2);
        v += __shfl_xor(v, 4);
        v += __shfl_xor(v, 8);
        dsp[k] = v;
    }
    if (l16 == 0) {
        #pragma unroll
        for (int a = 0; a < 2; ++a)
            #pragma unroll
            for (int r = 0; r < 4; ++r) {
                const int row = r0 + a * 16 + quad * 4 + r;
                dsred[(w & 1) * 64 + row] = dsp[a * 4 + r];
            }
    }
    __syncthreads();
    if (t < 64)
        dsp_o[(size_t)jq * B_ * N_ + (size_t)b * N_ + it0 + t]
            = f2bf(dsred[t] + dsred[64 + t]);
}

// ---------------- combine: out = sum of the four j-quarter bf16 partials ----------------
__global__ __launch_bounds__(256)
void combine_kernel(const unsigned short* __restrict__ dvp,
                    const unsigned short* __restrict__ dsp,
                    float* __restrict__ out) {
    const size_t nE  = (size_t)B_ * N_ * D_;
    const int  NDV8  = B_ * N_ * D_ / 8;   // 524288
    const int  NDS   = B_ * N_;            // 16384
    int x = blockIdx.x * 256 + threadIdx.x;
    if (x < NDV8) {
        float acc[8];
        #pragma unroll
        for (int i = 0; i < 8; ++i) acc[i] = 0.f;
        #pragma unroll
        for (int q = 0; q < 4; ++q) {
            ushort8v v = *(const ushort8v*)(dvp + q * nE + (size_t)x * 8);
            #pragma unroll
            for (int i = 0; i < 8; ++i) acc[i] += bf2f(v[i]);
        }
        float4 r0, r1;
        r0.x = acc[0]; r0.y = acc[1]; r0.z = acc[2]; r0.w = acc[3];
        r1.x = acc[4]; r1.y = acc[5]; r1.z = acc[6]; r1.w = acc[7];
        *(float4*)(out + NDS + (size_t)x * 8)     = r0;
        *(float4*)(out + NDS + (size_t)x * 8 + 4) = r1;
    } else {
        int y = (x - NDV8) * 4;
        if (y < NDS) {
            float a0 = 0.f, a1 = 0.f, a2 = 0.f, a3 = 0.f;
            #pragma unroll
            for (int q = 0; q < 4; ++q) {
                ushort4 v = *(const ushort4*)(dsp + q * NDS + y);
                a0 += bf2f(v.x); a1 += bf2f(v.y);
                a2 += bf2f(v.z); a3 += bf2f(v.w);
            }
            float4 r; r.x = a0; r.y = a1; r.z = a2; r.w = a3;
            *(float4*)(out + y) = r;
        }
    }
}

// ---------------- fallback (round-1 kernel, used if ws too small) ----------------
__global__ __launch_bounds__(256, 1)
void prop_kernel_fb(const float* __restrict__ val,
                    const float* __restrict__ state,
                    float* __restrict__ out) {
    __shared__ __attribute__((aligned(16))) unsigned short vi[64][264];
    __shared__ __attribute__((aligned(16))) unsigned short vj[64][264];
    __shared__ __attribute__((aligned(16))) unsigned short vjt[2048][8];
    __shared__ __attribute__((aligned(16))) unsigned short Esh[64][72];
    __shared__ float stj[64];
    __shared__ float dsred[2][64];

    const int t    = threadIdx.x;
    const int w    = t >> 6;
    const int lane = t & 63;
    const int quad = lane >> 4;
    const int l16  = lane & 15;
    const int b   = blockIdx.x >> 6;
    const int it0 = (blockIdx.x & 63) << 6;
    const float* valb = val   + (size_t)b * N_ * D_;
    const float* stb  = state + (size_t)b * N_;

    #pragma unroll
    for (int n = 0; n < 16; ++n) {
        int idx = t + 256 * n;
        int row = idx >> 6;
        int c4  = idx & 63;
        float4 v = *(const float4*)(valb + (size_t)(it0 + row) * D_ + c4 * 4);
        ushort4 h;
        h.x = f2bf(v.x); h.y = f2bf(v.y); h.z = f2bf(v.z); h.w = f2bf(v.w);
        *(ushort4*)&vi[row][c4 * 4] = h;
    }

    const int r0 = (w >> 1) * 32;
    const int c0 = (w & 1) * 32;
    floatx4 dv[4][4];
    #pragma unroll
    for (int a = 0; a < 4; ++a)
        #pragma unroll
        for (int c = 0; c < 4; ++c)
            dv[a][c] = (floatx4){0.f, 0.f, 0.f, 0.f};
    float dsp[8];
    #pragma unroll
    for (int k = 0; k < 8; ++k) dsp[k] = 0.f;

    for (int jt = 0; jt < 64; ++jt) {
        const int j0 = jt * 64;
        #pragma unroll
        for (int n = 0; n < 16; ++n) {
            int idx = t + 256 * n;
            int row = idx >> 6;
            int c4  = idx & 63;
            float4 v = *(const float4*)(valb + (size_t)(j0 + row) * D_ + c4 * 4);
            ushort4 h;
            h.x = f2bf(v.x); h.y = f2bf(v.y); h.z = f2bf(v.z); h.w = f2bf(v.w);
            *(ushort4*)&vj[row][c4 * 4] = h;
        }
        if (t < 64) stj[t] = stb[j0 + t];
        __syncthreads();

        #pragma unroll
        for (int n = 0; n < 8; ++n) {
            const int d  = t;
            const int jb = n;
            short8 pk;
            #pragma unroll
            for (int jj = 0; jj < 8; ++jj) pk[jj] = (short)vj[jb * 8 + jj][d];
            *(short8*)&vjt[d * 8 + (jb ^ (d & 7))][0] = pk;
        }

        floatx4 sa[2][2];
        #pragma unroll
        for (int a = 0; a < 2; ++a)
            #pragma unroll
            for (int c = 0; c < 2; ++c)
                sa[a][c] = (floatx4){0.f, 0.f, 0.f, 0.f};
        #pragma unroll
        for (int ks = 0; ks < 8; ++ks) {
            const int d0 = ks * 32 + quad * 8;
            short8 a0 = *(const short8*)&vi[r0 + l16][d0];
            short8 a1 = *(const short8*)&vi[r0 + 16 + l16][d0];
            short8 b0 = *(const short8*)&vj[c0 + l16][d0];
            short8 b1 = *(const short8*)&vj[c0 + 16 + l16][d0];
            sa[0][0] = __builtin_amdgcn_mfma_f32_16x16x32_bf16(a0, b0, sa[0][0], 0, 0, 0);
            sa[0][1] = __builtin_amdgcn_mfma_f32_16x16x32_bf16(a0, b1, sa[0][1], 0, 0, 0);
            sa[1][0] = __builtin_amdgcn_mfma_f32_16x16x32_bf16(a1, b0, sa[1][0], 0, 0, 0);
            sa[1][1] = __builtin_amdgcn_mfma_f32_16x16x32_bf16(a1, b1, sa[1][1], 0, 0, 0);
        }

        float stc0 = stj[c0 + l16];
        float stc1 = stj[c0 + 16 + l16];
        #pragma unroll
        for (int a = 0; a < 2; ++a) {
            #pragma unroll
            for (int r = 0; r < 4; ++r) {
                const int il = r0 + a * 16 + quad * 4 + r;
                float s0 = sa[a][0][r] * 0.0625f;
                float s1 = sa[a][1][r] * 0.0625f;
                float e0 = s0 / (1.0f + fabsf(s0));
                float e1 = s1 / (1.0f + fabsf(s1));
                dsp[a * 4 + r] += e0 * stc0 + e1 * stc1;
                Esh[il][c0 + l16]      = f2bf(e0);
                Esh[il][c0 + 16 + l16] = f2bf(e1);
            }
        }
        __syncthreads();

        #pragma unroll
        for (int ks = 0; ks < 2; ++ks) {
            short8 af[4], bfr[4];
            #pragma unroll
            for (int a2 = 0; a2 < 4; ++a2)
                af[a2] = *(const short8*)&Esh[a2 * 16 + l16][ks * 32 + quad * 8];
            #pragma unroll
            for (int c2 = 0; c2 < 4; ++c2) {
                const int d  = w * 64 + c2 * 16 + l16;
                const int jb = ks * 4 + quad;
                bfr[c2] = *(const short8*)&vjt[d * 8 + (jb ^ (d & 7))][0];
            }
            #pragma unroll
            for (int a2 = 0; a2 < 4; ++a2)
                #pragma unroll
                for (int c2 = 0; c2 < 4; ++c2)
                    dv[a2][c2] = __builtin_amdgcn_mfma_f32_16x16x32_bf16(af[a2], bfr[c2], dv[a2][c2], 0, 0, 0);
        }
    }

    float* dvo = out + (size_t)B_ * N_ + (size_t)b * N_ * D_;
    #pragma unroll
    for (int a2 = 0; a2 < 4; ++a2)
        #pragma unroll
        for (int c2 = 0; c2 < 4; ++c2)
            #pragma unroll
            for (int r = 0; r < 4; ++r) {
                const int i = it0 + a2 * 16 + quad * 4 + r;
                const int d = w * 64 + c2 * 16 + l16;
                dvo[(size_t)i * D_ + d] = dv[a2][c2][r];
            }

    #pragma unroll
    for (int k = 0; k < 8; ++k) {
        float v = dsp[k];
        v += __shfl_xor(v, 1);
        v += __shfl_xor(v, 2);
        v += __shfl_xor(v, 4);
        v += __shfl_xor(v, 8);
        dsp[k] = v;
    }
    if (l16 == 0) {
        #pragma unroll
        for (int a = 0; a < 2; ++a)
            #pragma unroll
            for (int r = 0; r < 4; ++r) {
                const int row = (w >> 1) * 32 + a * 16 + quad * 4 + r;
                dsred[w & 1][row] = dsp[a * 4 + r];
            }
    }
    __syncthreads();
    if (t < 64) out[(size_t)b * N_ + it0 + t] = dsred[0][t] + dsred[1][t];
}

extern "C" void kernel_launch(void* const* d_in, const int* in_sizes, int n_in,
                              void* d_out, int out_size, void* d_ws, size_t ws_size,
                              hipStream_t stream) {
    const float* val   = (const float*)d_in[0];
    const float* state = (const float*)d_in[1];
    float* out = (float*)d_out;

    const size_t nE         = (size_t)B_ * N_ * D_;                 // 4,194,304
    // Vb + VF (bf16) + 4x dv partials (bf16) + 4x ds partials (bf16)
    const size_t need_split = 2 * nE * sizeof(unsigned short)
                            + 4 * nE * sizeof(unsigned short)
                            + 4 * (size_t)B_ * N_ * sizeof(unsigned short);
                            // = 50,462,720 (same as prior rounds)

    if (ws_size >= need_split) {
        unsigned short* Vb  = (unsigned short*)d_ws;
        unsigned short* VF  = Vb + nE;
        unsigned short* dvp = VF + nE;                    // [4][B*N*D] bf16
        unsigned short* dsp = dvp + 4 * nE;               // [4][B*N]   bf16
        prepass_kernel<<<dim3(1024), dim3(256), 0, stream>>>(val, Vb, VF);
        prop_main<<<dim3(1024), dim3(256), 0, stream>>>(state, Vb, VF, dvp, dsp);
        const int NDV8 = B_ * N_ * D_ / 8;   // 524288
        const int NDS4 = B_ * N_ / 4;        // 4096
        combine_kernel<<<dim3((NDV8 + NDS4 + 255) / 256), dim3(256), 0, stream>>>(
            dvp, dsp, out);
    } else {
        prop_kernel_fb<<<dim3(256), dim3(256), 0, stream>>>(val, state, out);
    }
}